// Round 8
// baseline (1045.208 us; speedup 1.0000x reference)
//
#include <hip/hip_runtime.h>
#include <stdint.h>

// ---------------------------------------------------------------------------
// 2-layer GCN: relu(gcn(x,W1,b1)) -> batchnorm -> relu(gcn(.,W2,b2))
// n=100000, E=1.6M, f_in=25, hid=128.
// R2: parallel scan (947 -> 681 us).
// R6: gemm2 128x128 tile + bf16 intermediates (681 -> 593 us).
// R7: scatter_kernel had 16x write amplification (105MB writes for a 6.4MB
//     array; random 4B stores -> full-line writebacks; 130us). Replaced by
//     two-phase bucketed scatter: binA scatters (src,tgt) pairs into 256-node
//     bucket regions (sequential-within-bucket allocation -> full lines),
//     binB sorts each bucket via LDS cursors into its contiguous edge_src
//     region (cache-resident writes). Scan chunk now 256 so bucket offsets
//     == rowptr[b*256]; global cursor array eliminated.
// R8: resubmit — R7 bench died on the same unresponsive container (infra).
// ---------------------------------------------------------------------------

#define HID 128

__device__ __forceinline__ unsigned short f2bf(float f) {
    unsigned int u = __float_as_uint(f);
    unsigned int r = (u + 0x7FFFu + ((u >> 16) & 1u)) >> 16;  // RNE
    return (unsigned short)r;
}
__device__ __forceinline__ unsigned int pack2bf(float lo, float hi) {
    return (unsigned int)f2bf(lo) | ((unsigned int)f2bf(hi) << 16);
}

// --- detect whether edge_index buffer is int64 or int32 --------------------
__global__ void detect_kernel(const unsigned int* __restrict__ w, int* __restrict__ mode, int nwords) {
    __shared__ int any;
    if (threadIdx.x == 0) any = 0;
    __syncthreads();
    for (int i = threadIdx.x * 2 + 1; i < nwords && i < 8192; i += 512) {
        if (w[i] != 0) atomicOr(&any, 1);
    }
    __syncthreads();
    if (threadIdx.x == 0) *mode = any ? 0 : 1;  // 1 => int64 layout
}

__device__ __forceinline__ int load_idx(const void* ei, size_t i, int mode) {
    return mode ? (int)((const long long*)ei)[i] : ((const int*)ei)[i];
}

// --- in-degree histogram (targets = col) -----------------------------------
__global__ void count_kernel(const void* __restrict__ ei, const int* __restrict__ modep,
                             int* __restrict__ cnt, int E) {
    int e = blockIdx.x * blockDim.x + threadIdx.x;
    if (e >= E) return;
    int mode = *modep;
    int c = load_idx(ei, (size_t)E + e, mode);
    atomicAdd(&cnt[c], 1);
}

// --- scan phase 1: per-256-chunk sums (chunk == bucket) --------------------
__global__ __launch_bounds__(256) void scan_partial_kernel(const int* __restrict__ cnt,
                                                           int* __restrict__ blocksum, int n) {
    int i = blockIdx.x * 256 + threadIdx.x;
    int s = (i < n) ? cnt[i] : 0;
    #pragma unroll
    for (int off = 32; off > 0; off >>= 1) s += __shfl_down(s, off);
    __shared__ int ls[4];
    if ((threadIdx.x & 63) == 0) ls[threadIdx.x >> 6] = s;
    __syncthreads();
    if (threadIdx.x == 0) blocksum[blockIdx.x] = ls[0] + ls[1] + ls[2] + ls[3];
}

// --- scan phase 2: scan block sums (nb <= 1024); also init bucket cursors --
__global__ __launch_bounds__(1024) void scan_blocksums_kernel(const int* __restrict__ blocksum,
                                                              int* __restrict__ blockoff,
                                                              int* __restrict__ bucket_cur,
                                                              int* __restrict__ rowptr,
                                                              int nb, int n) {
    __shared__ int s[1024];
    int t = threadIdx.x;
    int own = (t < nb) ? blocksum[t] : 0;
    s[t] = own;
    __syncthreads();
    for (int off = 1; off < 1024; off <<= 1) {
        int v = s[t] + ((t >= off) ? s[t - off] : 0);
        __syncthreads();
        s[t] = v;
        __syncthreads();
    }
    if (t < nb) { blockoff[t] = s[t] - own; bucket_cur[t] = s[t] - own; }
    if (t == 1023) rowptr[n] = s[1023];    // total
}

// --- scan phase 3: per-element exclusive prefix + dinv ---------------------
__global__ __launch_bounds__(256) void scan_finalize_kernel(const int* __restrict__ cnt,
                                                            const int* __restrict__ blockoff,
                                                            int* __restrict__ rowptr,
                                                            float* __restrict__ dinv, int n) {
    int t = threadIdx.x;
    int i = blockIdx.x * 256 + t;
    int own = (i < n) ? cnt[i] : 0;
    __shared__ int s[256];
    s[t] = own;
    __syncthreads();
    for (int off = 1; off < 256; off <<= 1) {
        int x = s[t] + ((t >= off) ? s[t - off] : 0);
        __syncthreads();
        s[t] = x;
        __syncthreads();
    }
    if (i < n) {
        rowptr[i] = blockoff[blockIdx.x] + s[t] - own;
        dinv[i] = rsqrtf((float)(own + 1));  // +1 self loop
    }
}

// --- binA: scatter (src,tgt) pairs into 256-node bucket regions ------------
__global__ void bin_kernel(const void* __restrict__ ei, const int* __restrict__ modep,
                           int* __restrict__ bucket_cur, uint2* __restrict__ pairs, int E) {
    int e = blockIdx.x * blockDim.x + threadIdx.x;
    if (e >= E) return;
    int mode = *modep;
    int r = load_idx(ei, (size_t)e, mode);
    int c = load_idx(ei, (size_t)E + e, mode);
    int p = atomicAdd(&bucket_cur[c >> 8], 1);
    pairs[p] = make_uint2((unsigned)r, (unsigned)c);
}

// --- binB: per-bucket LDS-cursor sort into contiguous edge_src region ------
__global__ __launch_bounds__(256) void bucket_scatter_kernel(
    const uint2* __restrict__ pairs, const int* __restrict__ rowptr,
    int* __restrict__ edge_src, int n) {
    int b = blockIdx.x;
    int node0 = b << 8;
    int t = threadIdx.x;
    __shared__ int cur[256];
    int node = node0 + t;
    cur[t] = (node < n) ? rowptr[node] : 0;
    int hi = node0 + 256; if (hi > n) hi = n;
    int sbeg = rowptr[node0];
    int send = rowptr[hi];
    __syncthreads();
    for (int i = sbeg + t; i < send; i += 256) {
        uint2 pr = pairs[i];
        int pos = atomicAdd(&cur[pr.y & 255], 1);
        edge_src[pos] = (int)pr.x;
    }
}

// --- GEMM1: h = bf16(x @ W1)   (K=25, W1 staged in LDS) --------------------
__global__ __launch_bounds__(256) void gemm1_kernel(const float* __restrict__ x,
                                                    const float* __restrict__ W,
                                                    unsigned short* __restrict__ h, int n) {
    __shared__ float lw[25 * HID];
    for (int i = threadIdx.x; i < 25 * HID; i += 256) lw[i] = W[i];
    __syncthreads();
    int g = threadIdx.x >> 7, c = threadIdx.x & 127;
    for (int r = blockIdx.x * 2 + g; r < n; r += gridDim.x * 2) {
        const float* xr = x + (size_t)r * 25;
        float acc = 0.f;
        #pragma unroll
        for (int k = 0; k < 25; ++k) acc = fmaf(xr[k], lw[k * HID + c], acc);
        h[(size_t)r * HID + c] = f2bf(acc);
    }
}

// --- propagation: out[c] = relu(dinv[c]*(sum_e h[src]*dinv[src] + h[c]*dinv[c]) + b)
__global__ __launch_bounds__(256) void propagate_kernel(
    const unsigned short* __restrict__ h, const int* __restrict__ rowptr,
    const int* __restrict__ edge_src, const float* __restrict__ dinv,
    const float* __restrict__ bias, float* __restrict__ out, int n) {
    int wid = (blockIdx.x * 256 + threadIdx.x) >> 6;
    if (wid >= n) return;
    int lane = threadIdx.x & 63;
    int beg = rowptr[wid], end = rowptr[wid + 1];
    float dc = dinv[wid];
    float ax = 0.f, ay = 0.f;
    const unsigned int* hp = (const unsigned int*)h;  // 64 uints per row
    for (int b = beg; b < end; b += 64) {
        int m = end - b; if (m > 64) m = 64;
        int s = 0; float w = 0.f;
        if (lane < m) { s = edge_src[b + lane]; w = dinv[s]; }
        for (int j = 0; j < m; ++j) {
            int sj = __shfl(s, j);
            float wj = __shfl(w, j);
            unsigned int v = hp[(size_t)sj * 64 + lane];
            ax = fmaf(__uint_as_float(v << 16), wj, ax);
            ay = fmaf(__uint_as_float(v & 0xffff0000u), wj, ay);
        }
    }
    {   // self loop
        unsigned int v = hp[(size_t)wid * 64 + lane];
        ax = fmaf(__uint_as_float(v << 16), dc, ax);
        ay = fmaf(__uint_as_float(v & 0xffff0000u), dc, ay);
    }
    float bx = bias[lane * 2], by = bias[lane * 2 + 1];
    ax = fmaxf(fmaf(ax, dc, bx), 0.f);
    ay = fmaxf(fmaf(ay, dc, by), 0.f);
    *(float2*)(out + (size_t)wid * HID + lane * 2) = make_float2(ax, ay);
}

// --- BN stats: per-channel sum and sumsq -----------------------------------
__global__ __launch_bounds__(256) void bn_stats_kernel(const float* __restrict__ y,
                                                       float* __restrict__ sum,
                                                       float* __restrict__ sumsq, int n) {
    int c = threadIdx.x & 127;
    int g = threadIdx.x >> 7;
    float s = 0.f, s2 = 0.f;
    for (int r = blockIdx.x * 2 + g; r < n; r += gridDim.x * 2) {
        float v = y[(size_t)r * HID + c];
        s += v;
        s2 = fmaf(v, v, s2);
    }
    __shared__ float ls[256], ls2[256];
    ls[threadIdx.x] = s; ls2[threadIdx.x] = s2;
    __syncthreads();
    if (threadIdx.x < 128) {
        atomicAdd(&sum[c], ls[threadIdx.x] + ls[threadIdx.x + 128]);
        atomicAdd(&sumsq[c], ls2[threadIdx.x] + ls2[threadIdx.x + 128]);
    }
}

__global__ void bn_finalize_kernel(const float* __restrict__ sum, const float* __restrict__ sumsq,
                                   const float* __restrict__ gamma, const float* __restrict__ beta,
                                   float* __restrict__ scale, float* __restrict__ shift, float inv_n) {
    int c = threadIdx.x;
    float mean = sum[c] * inv_n;
    float var = sumsq[c] * inv_n - mean * mean;
    float sc = gamma[c] * rsqrtf(var + 1e-5f);
    scale[c] = sc;
    shift[c] = beta[c] - mean * sc;
}

// --- GEMM2: h2 = bf16(bn(y1) @ W2)  (K=128), BN fused into tile load -------
__global__ __launch_bounds__(256) void gemm2_kernel(
    const float* __restrict__ y, const float* __restrict__ W,
    const float* __restrict__ scale, const float* __restrict__ shift,
    unsigned short* __restrict__ out, int n) {
    __shared__ float lw[32][HID];       // [k][c] 16KB
    __shared__ float ly[32][132];       // [k][r] 16.5KB (pad: align + bank-free)
    int t = threadIdx.x;
    int base = blockIdx.x * 128;
    int c8 = (t & 15) * 8;   // col start (16 groups x 8 cols)
    int rg = t >> 4;         // 0..15, rows rg*8 .. rg*8+7
    float acc[8][8];
    #pragma unroll
    for (int r = 0; r < 8; ++r)
        #pragma unroll
        for (int c = 0; c < 8; ++c) acc[r][c] = 0.f;

    int sr = t & 127;        // staging row
    int sg = t >> 7;         // 0/1: which half of k
    for (int kc = 0; kc < 4; ++kc) {
        #pragma unroll
        for (int i = 0; i < 16; ++i) {
            int idx = t + i * 256;
            int kk = idx >> 7, cc = idx & 127;
            lw[kk][cc] = W[(size_t)(kc * 32 + kk) * HID + cc];
        }
        int gr = base + sr;
        #pragma unroll
        for (int i = 0; i < 4; ++i) {
            int k0 = (sg * 4 + i) * 4;
            float4 vy = make_float4(0.f, 0.f, 0.f, 0.f);
            if (gr < n) vy = *(const float4*)(y + (size_t)gr * HID + kc * 32 + k0);
            int gk = kc * 32 + k0;
            ly[k0 + 0][sr] = fmaf(vy.x, scale[gk + 0], shift[gk + 0]);
            ly[k0 + 1][sr] = fmaf(vy.y, scale[gk + 1], shift[gk + 1]);
            ly[k0 + 2][sr] = fmaf(vy.z, scale[gk + 2], shift[gk + 2]);
            ly[k0 + 3][sr] = fmaf(vy.w, scale[gk + 3], shift[gk + 3]);
        }
        __syncthreads();
        #pragma unroll
        for (int k = 0; k < 32; ++k) {
            float4 w0 = *(const float4*)&lw[k][c8];
            float4 w1 = *(const float4*)&lw[k][c8 + 4];
            float4 ya = *(const float4*)&ly[k][rg * 8];
            float4 yb = *(const float4*)&ly[k][rg * 8 + 4];
            float yv[8] = {ya.x, ya.y, ya.z, ya.w, yb.x, yb.y, yb.z, yb.w};
            float wv[8] = {w0.x, w0.y, w0.z, w0.w, w1.x, w1.y, w1.z, w1.w};
            #pragma unroll
            for (int r = 0; r < 8; ++r)
                #pragma unroll
                for (int c = 0; c < 8; ++c)
                    acc[r][c] = fmaf(yv[r], wv[c], acc[r][c]);
        }
        __syncthreads();
    }
    #pragma unroll
    for (int r = 0; r < 8; ++r) {
        int gr = base + rg * 8 + r;
        if (gr < n) {
            uint4 p;
            p.x = pack2bf(acc[r][0], acc[r][1]);
            p.y = pack2bf(acc[r][2], acc[r][3]);
            p.z = pack2bf(acc[r][4], acc[r][5]);
            p.w = pack2bf(acc[r][6], acc[r][7]);
            *(uint4*)&out[(size_t)gr * HID + c8] = p;
        }
    }
}

extern "C" void kernel_launch(void* const* d_in, const int* in_sizes, int n_in,
                              void* d_out, int out_size, void* d_ws, size_t ws_size,
                              hipStream_t stream) {
    const float* x     = (const float*)d_in[0];
    const void*  ei    = d_in[1];
    const float* W1    = (const float*)d_in[2];
    const float* b1    = (const float*)d_in[3];
    const float* gamma = (const float*)d_in[4];
    const float* beta  = (const float*)d_in[5];
    const float* W2    = (const float*)d_in[6];
    const float* b2    = (const float*)d_in[7];
    float* out = (float*)d_out;

    const int f_in = 25;
    int n = in_sizes[0] / f_in;
    int E = in_sizes[1] / 2;
    int nb = (n + 255) >> 8;   // 256-node buckets == scan chunks

    char* ws = (char*)d_ws;
    size_t off = 0;
    auto alloc = [&](size_t bytes) -> void* {
        void* p = ws + off;
        off += (bytes + 511) & ~(size_t)511;
        return p;
    };
    int*   cnt        = (int*)alloc((size_t)n * 4);
    int*   rowptr     = (int*)alloc(((size_t)n + 1) * 4);
    float* dinv       = (float*)alloc((size_t)n * 4);
    int*   edge_src   = (int*)alloc((size_t)E * 4);
    uint2* pairs      = (uint2*)alloc((size_t)E * 8);
    float* bnacc      = (float*)alloc(256 * 4);   // sum[128] ++ sumsq[128]
    float* sclshift   = (float*)alloc(256 * 4);   // scale[128] ++ shift[128]
    int*   mode       = (int*)alloc(4);
    int*   blocksum   = (int*)alloc((size_t)nb * 4);
    int*   blockoff   = (int*)alloc((size_t)nb * 4);
    int*   bucket_cur = (int*)alloc((size_t)nb * 4);
    unsigned short* h = (unsigned short*)alloc((size_t)n * HID * 2);  // bf16 h1, then h2

    hipMemsetAsync(cnt, 0, (size_t)n * 4, stream);
    hipMemsetAsync(bnacc, 0, 256 * 4, stream);

    detect_kernel<<<1, 256, 0, stream>>>((const unsigned int*)ei, mode, 2 * E);
    count_kernel<<<(E + 255) / 256, 256, 0, stream>>>(ei, mode, cnt, E);
    scan_partial_kernel<<<nb, 256, 0, stream>>>(cnt, blocksum, n);
    scan_blocksums_kernel<<<1, 1024, 0, stream>>>(blocksum, blockoff, bucket_cur, rowptr, nb, n);
    scan_finalize_kernel<<<nb, 256, 0, stream>>>(cnt, blockoff, rowptr, dinv, n);
    bin_kernel<<<(E + 255) / 256, 256, 0, stream>>>(ei, mode, bucket_cur, pairs, E);
    bucket_scatter_kernel<<<nb, 256, 0, stream>>>(pairs, rowptr, edge_src, n);

    // layer 1: h1 = bf16(x@W1) ; y1 = relu(prop(h1) + b1) -> stored in d_out (fp32)
    gemm1_kernel<<<4096, 256, 0, stream>>>(x, W1, h, n);
    propagate_kernel<<<(n + 3) / 4, 256, 0, stream>>>(h, rowptr, edge_src, dinv, b1, out, n);

    // batchnorm stats on y1
    bn_stats_kernel<<<512, 256, 0, stream>>>(out, bnacc, bnacc + 128, n);
    bn_finalize_kernel<<<1, 128, 0, stream>>>(bnacc, bnacc + 128, gamma, beta,
                                              sclshift, sclshift + 128, 1.0f / (float)n);

    // layer 2: h2 = bf16(bn(y1)@W2) ; out = relu(prop(h2) + b2)
    gemm2_kernel<<<(n + 127) / 128, 256, 0, stream>>>(out, W2, sclshift, sclshift + 128, h, n);
    propagate_kernel<<<(n + 3) / 4, 256, 0, stream>>>(h, rowptr, edge_src, dinv, b2, out, n);
}

// Round 9
// 601.308 us; speedup vs baseline: 1.7382x; 1.7382x over previous
//
#include <hip/hip_runtime.h>
#include <stdint.h>

// ---------------------------------------------------------------------------
// 2-layer GCN: relu(gcn(x,W1,b1)) -> batchnorm -> relu(gcn(.,W2,b2))
// n=100000, E=1.6M, f_in=25, hid=128.
// R2: parallel scan (947 -> 681 us).
// R6: gemm2 128x128 tile + bf16 intermediates (681 -> 593 us).
// R7/R8: bucketed scatter, bucket=tgt>>8 (391 counters) -> returning-atomic
//     serialization: 1.6M/391=4090 chained L2 atomics x ~136ns = 558us. BAD.
// R9: bucket=tgt>>3 (12500 counters): chain 128 x 136ns ~ 17us, write
//     locality preserved (1KB sequential region per bucket, lines fill).
//     binB unchanged (8-node buckets nest in its 256-node chunks).
// ---------------------------------------------------------------------------

#define HID 128

__device__ __forceinline__ unsigned short f2bf(float f) {
    unsigned int u = __float_as_uint(f);
    unsigned int r = (u + 0x7FFFu + ((u >> 16) & 1u)) >> 16;  // RNE
    return (unsigned short)r;
}
__device__ __forceinline__ unsigned int pack2bf(float lo, float hi) {
    return (unsigned int)f2bf(lo) | ((unsigned int)f2bf(hi) << 16);
}

// --- detect whether edge_index buffer is int64 or int32 --------------------
__global__ void detect_kernel(const unsigned int* __restrict__ w, int* __restrict__ mode, int nwords) {
    __shared__ int any;
    if (threadIdx.x == 0) any = 0;
    __syncthreads();
    for (int i = threadIdx.x * 2 + 1; i < nwords && i < 8192; i += 512) {
        if (w[i] != 0) atomicOr(&any, 1);
    }
    __syncthreads();
    if (threadIdx.x == 0) *mode = any ? 0 : 1;  // 1 => int64 layout
}

__device__ __forceinline__ int load_idx(const void* ei, size_t i, int mode) {
    return mode ? (int)((const long long*)ei)[i] : ((const int*)ei)[i];
}

// --- in-degree histogram (targets = col) -----------------------------------
__global__ void count_kernel(const void* __restrict__ ei, const int* __restrict__ modep,
                             int* __restrict__ cnt, int E) {
    int e = blockIdx.x * blockDim.x + threadIdx.x;
    if (e >= E) return;
    int mode = *modep;
    int c = load_idx(ei, (size_t)E + e, mode);
    atomicAdd(&cnt[c], 1);
}

// --- scan phase 1: per-256-chunk sums --------------------------------------
__global__ __launch_bounds__(256) void scan_partial_kernel(const int* __restrict__ cnt,
                                                           int* __restrict__ blocksum, int n) {
    int i = blockIdx.x * 256 + threadIdx.x;
    int s = (i < n) ? cnt[i] : 0;
    #pragma unroll
    for (int off = 32; off > 0; off >>= 1) s += __shfl_down(s, off);
    __shared__ int ls[4];
    if ((threadIdx.x & 63) == 0) ls[threadIdx.x >> 6] = s;
    __syncthreads();
    if (threadIdx.x == 0) blocksum[blockIdx.x] = ls[0] + ls[1] + ls[2] + ls[3];
}

// --- scan phase 2: scan block sums (nb <= 1024) ----------------------------
__global__ __launch_bounds__(1024) void scan_blocksums_kernel(const int* __restrict__ blocksum,
                                                              int* __restrict__ blockoff,
                                                              int* __restrict__ rowptr,
                                                              int nb, int n) {
    __shared__ int s[1024];
    int t = threadIdx.x;
    int own = (t < nb) ? blocksum[t] : 0;
    s[t] = own;
    __syncthreads();
    for (int off = 1; off < 1024; off <<= 1) {
        int v = s[t] + ((t >= off) ? s[t - off] : 0);
        __syncthreads();
        s[t] = v;
        __syncthreads();
    }
    if (t < nb) blockoff[t] = s[t] - own;  // exclusive
    if (t == 1023) rowptr[n] = s[1023];    // total
}

// --- scan phase 3: element prefix + dinv + 8-node-bucket cursor init -------
__global__ __launch_bounds__(256) void scan_finalize_kernel(const int* __restrict__ cnt,
                                                            const int* __restrict__ blockoff,
                                                            int* __restrict__ rowptr,
                                                            int* __restrict__ bucket_cur,
                                                            float* __restrict__ dinv, int n) {
    int t = threadIdx.x;
    int i = blockIdx.x * 256 + t;
    int own = (i < n) ? cnt[i] : 0;
    __shared__ int s[256];
    s[t] = own;
    __syncthreads();
    for (int off = 1; off < 256; off <<= 1) {
        int x = s[t] + ((t >= off) ? s[t - off] : 0);
        __syncthreads();
        s[t] = x;
        __syncthreads();
    }
    if (i < n) {
        int e0 = blockoff[blockIdx.x] + s[t] - own;
        rowptr[i] = e0;
        if ((i & 7) == 0) bucket_cur[i >> 3] = e0;  // bucket = 8 nodes
        dinv[i] = rsqrtf((float)(own + 1));  // +1 self loop
    }
}

// --- binA: scatter (src,tgt) pairs into 8-node bucket regions --------------
__global__ void bin_kernel(const void* __restrict__ ei, const int* __restrict__ modep,
                           int* __restrict__ bucket_cur, uint2* __restrict__ pairs, int E) {
    int e = blockIdx.x * blockDim.x + threadIdx.x;
    if (e >= E) return;
    int mode = *modep;
    int r = load_idx(ei, (size_t)e, mode);
    int c = load_idx(ei, (size_t)E + e, mode);
    int p = atomicAdd(&bucket_cur[c >> 3], 1);
    pairs[p] = make_uint2((unsigned)r, (unsigned)c);
}

// --- binB: per-256-node-chunk LDS-cursor sort into edge_src ----------------
// (8-node bucket regions nest inside the chunk region; any in-chunk order ok)
__global__ __launch_bounds__(256) void bucket_scatter_kernel(
    const uint2* __restrict__ pairs, const int* __restrict__ rowptr,
    int* __restrict__ edge_src, int n) {
    int b = blockIdx.x;
    int node0 = b << 8;
    int t = threadIdx.x;
    __shared__ int cur[256];
    int node = node0 + t;
    cur[t] = (node < n) ? rowptr[node] : 0;
    int hi = node0 + 256; if (hi > n) hi = n;
    int sbeg = rowptr[node0];
    int send = rowptr[hi];
    __syncthreads();
    for (int i = sbeg + t; i < send; i += 256) {
        uint2 pr = pairs[i];
        int pos = atomicAdd(&cur[pr.y & 255], 1);
        edge_src[pos] = (int)pr.x;
    }
}

// --- GEMM1: h = bf16(x @ W1)   (K=25, W1 staged in LDS) --------------------
__global__ __launch_bounds__(256) void gemm1_kernel(const float* __restrict__ x,
                                                    const float* __restrict__ W,
                                                    unsigned short* __restrict__ h, int n) {
    __shared__ float lw[25 * HID];
    for (int i = threadIdx.x; i < 25 * HID; i += 256) lw[i] = W[i];
    __syncthreads();
    int g = threadIdx.x >> 7, c = threadIdx.x & 127;
    for (int r = blockIdx.x * 2 + g; r < n; r += gridDim.x * 2) {
        const float* xr = x + (size_t)r * 25;
        float acc = 0.f;
        #pragma unroll
        for (int k = 0; k < 25; ++k) acc = fmaf(xr[k], lw[k * HID + c], acc);
        h[(size_t)r * HID + c] = f2bf(acc);
    }
}

// --- propagation: out[c] = relu(dinv[c]*(sum_e h[src]*dinv[src] + h[c]*dinv[c]) + b)
__global__ __launch_bounds__(256) void propagate_kernel(
    const unsigned short* __restrict__ h, const int* __restrict__ rowptr,
    const int* __restrict__ edge_src, const float* __restrict__ dinv,
    const float* __restrict__ bias, float* __restrict__ out, int n) {
    int wid = (blockIdx.x * 256 + threadIdx.x) >> 6;
    if (wid >= n) return;
    int lane = threadIdx.x & 63;
    int beg = rowptr[wid], end = rowptr[wid + 1];
    float dc = dinv[wid];
    float ax = 0.f, ay = 0.f;
    const unsigned int* hp = (const unsigned int*)h;  // 64 uints per row
    for (int b = beg; b < end; b += 64) {
        int m = end - b; if (m > 64) m = 64;
        int s = 0; float w = 0.f;
        if (lane < m) { s = edge_src[b + lane]; w = dinv[s]; }
        for (int j = 0; j < m; ++j) {
            int sj = __shfl(s, j);
            float wj = __shfl(w, j);
            unsigned int v = hp[(size_t)sj * 64 + lane];
            ax = fmaf(__uint_as_float(v << 16), wj, ax);
            ay = fmaf(__uint_as_float(v & 0xffff0000u), wj, ay);
        }
    }
    {   // self loop
        unsigned int v = hp[(size_t)wid * 64 + lane];
        ax = fmaf(__uint_as_float(v << 16), dc, ax);
        ay = fmaf(__uint_as_float(v & 0xffff0000u), dc, ay);
    }
    float bx = bias[lane * 2], by = bias[lane * 2 + 1];
    ax = fmaxf(fmaf(ax, dc, bx), 0.f);
    ay = fmaxf(fmaf(ay, dc, by), 0.f);
    *(float2*)(out + (size_t)wid * HID + lane * 2) = make_float2(ax, ay);
}

// --- BN stats: per-channel sum and sumsq -----------------------------------
__global__ __launch_bounds__(256) void bn_stats_kernel(const float* __restrict__ y,
                                                       float* __restrict__ sum,
                                                       float* __restrict__ sumsq, int n) {
    int c = threadIdx.x & 127;
    int g = threadIdx.x >> 7;
    float s = 0.f, s2 = 0.f;
    for (int r = blockIdx.x * 2 + g; r < n; r += gridDim.x * 2) {
        float v = y[(size_t)r * HID + c];
        s += v;
        s2 = fmaf(v, v, s2);
    }
    __shared__ float ls[256], ls2[256];
    ls[threadIdx.x] = s; ls2[threadIdx.x] = s2;
    __syncthreads();
    if (threadIdx.x < 128) {
        atomicAdd(&sum[c], ls[threadIdx.x] + ls[threadIdx.x + 128]);
        atomicAdd(&sumsq[c], ls2[threadIdx.x] + ls2[threadIdx.x + 128]);
    }
}

__global__ void bn_finalize_kernel(const float* __restrict__ sum, const float* __restrict__ sumsq,
                                   const float* __restrict__ gamma, const float* __restrict__ beta,
                                   float* __restrict__ scale, float* __restrict__ shift, float inv_n) {
    int c = threadIdx.x;
    float mean = sum[c] * inv_n;
    float var = sumsq[c] * inv_n - mean * mean;
    float sc = gamma[c] * rsqrtf(var + 1e-5f);
    scale[c] = sc;
    shift[c] = beta[c] - mean * sc;
}

// --- GEMM2: h2 = bf16(bn(y1) @ W2)  (K=128), BN fused into tile load -------
__global__ __launch_bounds__(256) void gemm2_kernel(
    const float* __restrict__ y, const float* __restrict__ W,
    const float* __restrict__ scale, const float* __restrict__ shift,
    unsigned short* __restrict__ out, int n) {
    __shared__ float lw[32][HID];       // [k][c] 16KB
    __shared__ float ly[32][132];       // [k][r] 16.5KB (pad: align + bank-free)
    int t = threadIdx.x;
    int base = blockIdx.x * 128;
    int c8 = (t & 15) * 8;   // col start (16 groups x 8 cols)
    int rg = t >> 4;         // 0..15, rows rg*8 .. rg*8+7
    float acc[8][8];
    #pragma unroll
    for (int r = 0; r < 8; ++r)
        #pragma unroll
        for (int c = 0; c < 8; ++c) acc[r][c] = 0.f;

    int sr = t & 127;        // staging row
    int sg = t >> 7;         // 0/1: which half of k
    for (int kc = 0; kc < 4; ++kc) {
        #pragma unroll
        for (int i = 0; i < 16; ++i) {
            int idx = t + i * 256;
            int kk = idx >> 7, cc = idx & 127;
            lw[kk][cc] = W[(size_t)(kc * 32 + kk) * HID + cc];
        }
        int gr = base + sr;
        #pragma unroll
        for (int i = 0; i < 4; ++i) {
            int k0 = (sg * 4 + i) * 4;
            float4 vy = make_float4(0.f, 0.f, 0.f, 0.f);
            if (gr < n) vy = *(const float4*)(y + (size_t)gr * HID + kc * 32 + k0);
            int gk = kc * 32 + k0;
            ly[k0 + 0][sr] = fmaf(vy.x, scale[gk + 0], shift[gk + 0]);
            ly[k0 + 1][sr] = fmaf(vy.y, scale[gk + 1], shift[gk + 1]);
            ly[k0 + 2][sr] = fmaf(vy.z, scale[gk + 2], shift[gk + 2]);
            ly[k0 + 3][sr] = fmaf(vy.w, scale[gk + 3], shift[gk + 3]);
        }
        __syncthreads();
        #pragma unroll
        for (int k = 0; k < 32; ++k) {
            float4 w0 = *(const float4*)&lw[k][c8];
            float4 w1 = *(const float4*)&lw[k][c8 + 4];
            float4 ya = *(const float4*)&ly[k][rg * 8];
            float4 yb = *(const float4*)&ly[k][rg * 8 + 4];
            float yv[8] = {ya.x, ya.y, ya.z, ya.w, yb.x, yb.y, yb.z, yb.w};
            float wv[8] = {w0.x, w0.y, w0.z, w0.w, w1.x, w1.y, w1.z, w1.w};
            #pragma unroll
            for (int r = 0; r < 8; ++r)
                #pragma unroll
                for (int c = 0; c < 8; ++c)
                    acc[r][c] = fmaf(yv[r], wv[c], acc[r][c]);
        }
        __syncthreads();
    }
    #pragma unroll
    for (int r = 0; r < 8; ++r) {
        int gr = base + rg * 8 + r;
        if (gr < n) {
            uint4 p;
            p.x = pack2bf(acc[r][0], acc[r][1]);
            p.y = pack2bf(acc[r][2], acc[r][3]);
            p.z = pack2bf(acc[r][4], acc[r][5]);
            p.w = pack2bf(acc[r][6], acc[r][7]);
            *(uint4*)&out[(size_t)gr * HID + c8] = p;
        }
    }
}

extern "C" void kernel_launch(void* const* d_in, const int* in_sizes, int n_in,
                              void* d_out, int out_size, void* d_ws, size_t ws_size,
                              hipStream_t stream) {
    const float* x     = (const float*)d_in[0];
    const void*  ei    = d_in[1];
    const float* W1    = (const float*)d_in[2];
    const float* b1    = (const float*)d_in[3];
    const float* gamma = (const float*)d_in[4];
    const float* beta  = (const float*)d_in[5];
    const float* W2    = (const float*)d_in[6];
    const float* b2    = (const float*)d_in[7];
    float* out = (float*)d_out;

    const int f_in = 25;
    int n = in_sizes[0] / f_in;
    int E = in_sizes[1] / 2;
    int nb = (n + 255) >> 8;    // 256-node scan chunks
    int nbk = (n + 7) >> 3;     // 8-node buckets

    char* ws = (char*)d_ws;
    size_t off = 0;
    auto alloc = [&](size_t bytes) -> void* {
        void* p = ws + off;
        off += (bytes + 511) & ~(size_t)511;
        return p;
    };
    int*   cnt        = (int*)alloc((size_t)n * 4);
    int*   rowptr     = (int*)alloc(((size_t)n + 1) * 4);
    float* dinv       = (float*)alloc((size_t)n * 4);
    int*   edge_src   = (int*)alloc((size_t)E * 4);
    uint2* pairs      = (uint2*)alloc((size_t)E * 8);
    float* bnacc      = (float*)alloc(256 * 4);   // sum[128] ++ sumsq[128]
    float* sclshift   = (float*)alloc(256 * 4);   // scale[128] ++ shift[128]
    int*   mode       = (int*)alloc(4);
    int*   blocksum   = (int*)alloc((size_t)nb * 4);
    int*   blockoff   = (int*)alloc((size_t)nb * 4);
    int*   bucket_cur = (int*)alloc((size_t)nbk * 4);
    unsigned short* h = (unsigned short*)alloc((size_t)n * HID * 2);  // bf16 h1, then h2

    hipMemsetAsync(cnt, 0, (size_t)n * 4, stream);
    hipMemsetAsync(bnacc, 0, 256 * 4, stream);

    detect_kernel<<<1, 256, 0, stream>>>((const unsigned int*)ei, mode, 2 * E);
    count_kernel<<<(E + 255) / 256, 256, 0, stream>>>(ei, mode, cnt, E);
    scan_partial_kernel<<<nb, 256, 0, stream>>>(cnt, blocksum, n);
    scan_blocksums_kernel<<<1, 1024, 0, stream>>>(blocksum, blockoff, rowptr, nb, n);
    scan_finalize_kernel<<<nb, 256, 0, stream>>>(cnt, blockoff, rowptr, bucket_cur, dinv, n);
    bin_kernel<<<(E + 255) / 256, 256, 0, stream>>>(ei, mode, bucket_cur, pairs, E);
    bucket_scatter_kernel<<<nb, 256, 0, stream>>>(pairs, rowptr, edge_src, n);

    // layer 1: h1 = bf16(x@W1) ; y1 = relu(prop(h1) + b1) -> stored in d_out (fp32)
    gemm1_kernel<<<4096, 256, 0, stream>>>(x, W1, h, n);
    propagate_kernel<<<(n + 3) / 4, 256, 0, stream>>>(h, rowptr, edge_src, dinv, b1, out, n);

    // batchnorm stats on y1
    bn_stats_kernel<<<512, 256, 0, stream>>>(out, bnacc, bnacc + 128, n);
    bn_finalize_kernel<<<1, 128, 0, stream>>>(bnacc, bnacc + 128, gamma, beta,
                                              sclshift, sclshift + 128, 1.0f / (float)n);

    // layer 2: h2 = bf16(bn(y1)@W2) ; out = relu(prop(h2) + b2)
    gemm2_kernel<<<(n + 127) / 128, 256, 0, stream>>>(out, W2, sclshift, sclshift + 128, h, n);
    propagate_kernel<<<(n + 3) / 4, 256, 0, stream>>>(h, rowptr, edge_src, dinv, b2, out, n);
}

// Round 12
// 546.315 us; speedup vs baseline: 1.9132x; 1.1007x over previous
//
#include <hip/hip_runtime.h>
#include <stdint.h>

// ---------------------------------------------------------------------------
// 2-layer GCN: relu(gcn(x,W1,b1)) -> batchnorm -> relu(gcn(.,W2,b2))
// n=100000, E=1.6M, f_in=25, hid=128.
// R2: parallel scan (947 -> 681 us).
// R6: gemm2 128x128 tile + bf16 intermediates (681 -> 593 us).
// R8: bucket=tgt>>8 scatter -> returning-atomic chains on 391 counters, 558us.
// R9: bucket=tgt>>3: atomics fixed (120us) but 7x write amplification remains:
//     pair-lines are filled by waves on DIFFERENT XCDs -> partial dirty lines
//     in per-XCD L2s -> partial-line writebacks. ~0.86 TB/s ceiling.
// R10: XCD-partitioned DIRECT scatter: group g=(tgt>>4)&7 handled only by
//     blocks with blockIdx&7==g (round-robin dispatch => same XCD). Each
//     16-node granule's edge_src region is written by one XCD -> full-line
//     assembly, ~6.4MB writes. Cost: 8x streaming reads of edge_index
//     (L3-resident). pairs[] and binB pass eliminated. Mapping drift only
//     costs speed, never correctness.
// R11/R12: resubmits — benches died on the same unresponsive container (infra).
// ---------------------------------------------------------------------------

#define HID 128

__device__ __forceinline__ unsigned short f2bf(float f) {
    unsigned int u = __float_as_uint(f);
    unsigned int r = (u + 0x7FFFu + ((u >> 16) & 1u)) >> 16;  // RNE
    return (unsigned short)r;
}
__device__ __forceinline__ unsigned int pack2bf(float lo, float hi) {
    return (unsigned int)f2bf(lo) | ((unsigned int)f2bf(hi) << 16);
}

// --- detect whether edge_index buffer is int64 or int32 --------------------
__global__ void detect_kernel(const unsigned int* __restrict__ w, int* __restrict__ mode, int nwords) {
    __shared__ int any;
    if (threadIdx.x == 0) any = 0;
    __syncthreads();
    for (int i = threadIdx.x * 2 + 1; i < nwords && i < 8192; i += 512) {
        if (w[i] != 0) atomicOr(&any, 1);
    }
    __syncthreads();
    if (threadIdx.x == 0) *mode = any ? 0 : 1;  // 1 => int64 layout
}

__device__ __forceinline__ int load_idx(const void* ei, size_t i, int mode) {
    return mode ? (int)((const long long*)ei)[i] : ((const int*)ei)[i];
}

// --- in-degree histogram (targets = col) -----------------------------------
__global__ void count_kernel(const void* __restrict__ ei, const int* __restrict__ modep,
                             int* __restrict__ cnt, int E) {
    int e = blockIdx.x * blockDim.x + threadIdx.x;
    if (e >= E) return;
    int mode = *modep;
    int c = load_idx(ei, (size_t)E + e, mode);
    atomicAdd(&cnt[c], 1);  // non-returning: HW wave-coalesced
}

// --- scan phase 1: per-256-chunk sums --------------------------------------
__global__ __launch_bounds__(256) void scan_partial_kernel(const int* __restrict__ cnt,
                                                           int* __restrict__ blocksum, int n) {
    int i = blockIdx.x * 256 + threadIdx.x;
    int s = (i < n) ? cnt[i] : 0;
    #pragma unroll
    for (int off = 32; off > 0; off >>= 1) s += __shfl_down(s, off);
    __shared__ int ls[4];
    if ((threadIdx.x & 63) == 0) ls[threadIdx.x >> 6] = s;
    __syncthreads();
    if (threadIdx.x == 0) blocksum[blockIdx.x] = ls[0] + ls[1] + ls[2] + ls[3];
}

// --- scan phase 2: scan block sums (nb <= 1024) ----------------------------
__global__ __launch_bounds__(1024) void scan_blocksums_kernel(const int* __restrict__ blocksum,
                                                              int* __restrict__ blockoff,
                                                              int* __restrict__ rowptr,
                                                              int nb, int n) {
    __shared__ int s[1024];
    int t = threadIdx.x;
    int own = (t < nb) ? blocksum[t] : 0;
    s[t] = own;
    __syncthreads();
    for (int off = 1; off < 1024; off <<= 1) {
        int v = s[t] + ((t >= off) ? s[t - off] : 0);
        __syncthreads();
        s[t] = v;
        __syncthreads();
    }
    if (t < nb) blockoff[t] = s[t] - own;  // exclusive
    if (t == 1023) rowptr[n] = s[1023];    // total
}

// --- scan phase 3: element prefix + dinv + per-node cursor init ------------
__global__ __launch_bounds__(256) void scan_finalize_kernel(const int* __restrict__ cnt,
                                                            const int* __restrict__ blockoff,
                                                            int* __restrict__ rowptr,
                                                            int* __restrict__ cursor,
                                                            float* __restrict__ dinv, int n) {
    int t = threadIdx.x;
    int i = blockIdx.x * 256 + t;
    int own = (i < n) ? cnt[i] : 0;
    __shared__ int s[256];
    s[t] = own;
    __syncthreads();
    for (int off = 1; off < 256; off <<= 1) {
        int x = s[t] + ((t >= off) ? s[t - off] : 0);
        __syncthreads();
        s[t] = x;
        __syncthreads();
    }
    if (i < n) {
        int e0 = blockoff[blockIdx.x] + s[t] - own;
        rowptr[i] = e0;
        cursor[i] = e0;
        dinv[i] = rsqrtf((float)(own + 1));  // +1 self loop
    }
}

// --- XCD-partitioned direct scatter ----------------------------------------
// group g = blockIdx&7 (round-robin => XCD g in practice); group handles
// edges whose target granule (tgt>>4)&7 == g. Each group scans all E edges.
__global__ __launch_bounds__(256) void scatter_part_kernel(
    const void* __restrict__ ei, const int* __restrict__ modep,
    int* __restrict__ cursor, int* __restrict__ edge_src, int E) {
    int g = blockIdx.x & 7;
    int cb = blockIdx.x >> 3;          // chunk index within group
    int nchunks = gridDim.x >> 3;      // blocks per group
    int mode = *modep;
    int stride = nchunks * 256;
    for (int e = cb * 256 + threadIdx.x; e < E; e += stride) {
        int c = load_idx(ei, (size_t)E + e, mode);
        if (((c >> 4) & 7) != g) continue;
        int r = load_idx(ei, (size_t)e, mode);
        int pos = atomicAdd(&cursor[c], 1);
        edge_src[pos] = r;
    }
}

// --- GEMM1: h = bf16(x @ W1)   (K=25, W1 staged in LDS) --------------------
__global__ __launch_bounds__(256) void gemm1_kernel(const float* __restrict__ x,
                                                    const float* __restrict__ W,
                                                    unsigned short* __restrict__ h, int n) {
    __shared__ float lw[25 * HID];
    for (int i = threadIdx.x; i < 25 * HID; i += 256) lw[i] = W[i];
    __syncthreads();
    int g = threadIdx.x >> 7, c = threadIdx.x & 127;
    for (int r = blockIdx.x * 2 + g; r < n; r += gridDim.x * 2) {
        const float* xr = x + (size_t)r * 25;
        float acc = 0.f;
        #pragma unroll
        for (int k = 0; k < 25; ++k) acc = fmaf(xr[k], lw[k * HID + c], acc);
        h[(size_t)r * HID + c] = f2bf(acc);
    }
}

// --- propagation: out[c] = relu(dinv[c]*(sum_e h[src]*dinv[src] + h[c]*dinv[c]) + b)
__global__ __launch_bounds__(256) void propagate_kernel(
    const unsigned short* __restrict__ h, const int* __restrict__ rowptr,
    const int* __restrict__ edge_src, const float* __restrict__ dinv,
    const float* __restrict__ bias, float* __restrict__ out, int n) {
    int wid = (blockIdx.x * 256 + threadIdx.x) >> 6;
    if (wid >= n) return;
    int lane = threadIdx.x & 63;
    int beg = rowptr[wid], end = rowptr[wid + 1];
    float dc = dinv[wid];
    float ax = 0.f, ay = 0.f;
    const unsigned int* hp = (const unsigned int*)h;  // 64 uints per row
    for (int b = beg; b < end; b += 64) {
        int m = end - b; if (m > 64) m = 64;
        int s = 0; float w = 0.f;
        if (lane < m) { s = edge_src[b + lane]; w = dinv[s]; }
        for (int j = 0; j < m; ++j) {
            int sj = __shfl(s, j);
            float wj = __shfl(w, j);
            unsigned int v = hp[(size_t)sj * 64 + lane];
            ax = fmaf(__uint_as_float(v << 16), wj, ax);
            ay = fmaf(__uint_as_float(v & 0xffff0000u), wj, ay);
        }
    }
    {   // self loop
        unsigned int v = hp[(size_t)wid * 64 + lane];
        ax = fmaf(__uint_as_float(v << 16), dc, ax);
        ay = fmaf(__uint_as_float(v & 0xffff0000u), dc, ay);
    }
    float bx = bias[lane * 2], by = bias[lane * 2 + 1];
    ax = fmaxf(fmaf(ax, dc, bx), 0.f);
    ay = fmaxf(fmaf(ay, dc, by), 0.f);
    *(float2*)(out + (size_t)wid * HID + lane * 2) = make_float2(ax, ay);
}

// --- BN stats: per-channel sum and sumsq -----------------------------------
__global__ __launch_bounds__(256) void bn_stats_kernel(const float* __restrict__ y,
                                                       float* __restrict__ sum,
                                                       float* __restrict__ sumsq, int n) {
    int c = threadIdx.x & 127;
    int g = threadIdx.x >> 7;
    float s = 0.f, s2 = 0.f;
    for (int r = blockIdx.x * 2 + g; r < n; r += gridDim.x * 2) {
        float v = y[(size_t)r * HID + c];
        s += v;
        s2 = fmaf(v, v, s2);
    }
    __shared__ float ls[256], ls2[256];
    ls[threadIdx.x] = s; ls2[threadIdx.x] = s2;
    __syncthreads();
    if (threadIdx.x < 128) {
        atomicAdd(&sum[c], ls[threadIdx.x] + ls[threadIdx.x + 128]);
        atomicAdd(&sumsq[c], ls2[threadIdx.x] + ls2[threadIdx.x + 128]);
    }
}

__global__ void bn_finalize_kernel(const float* __restrict__ sum, const float* __restrict__ sumsq,
                                   const float* __restrict__ gamma, const float* __restrict__ beta,
                                   float* __restrict__ scale, float* __restrict__ shift, float inv_n) {
    int c = threadIdx.x;
    float mean = sum[c] * inv_n;
    float var = sumsq[c] * inv_n - mean * mean;
    float sc = gamma[c] * rsqrtf(var + 1e-5f);
    scale[c] = sc;
    shift[c] = beta[c] - mean * sc;
}

// --- GEMM2: h2 = bf16(bn(y1) @ W2)  (K=128), BN fused into tile load -------
__global__ __launch_bounds__(256) void gemm2_kernel(
    const float* __restrict__ y, const float* __restrict__ W,
    const float* __restrict__ scale, const float* __restrict__ shift,
    unsigned short* __restrict__ out, int n) {
    __shared__ float lw[32][HID];       // [k][c] 16KB
    __shared__ float ly[32][132];       // [k][r] 16.5KB (pad: align + bank-free)
    int t = threadIdx.x;
    int base = blockIdx.x * 128;
    int c8 = (t & 15) * 8;   // col start (16 groups x 8 cols)
    int rg = t >> 4;         // 0..15, rows rg*8 .. rg*8+7
    float acc[8][8];
    #pragma unroll
    for (int r = 0; r < 8; ++r)
        #pragma unroll
        for (int c = 0; c < 8; ++c) acc[r][c] = 0.f;

    int sr = t & 127;        // staging row
    int sg = t >> 7;         // 0/1: which half of k
    for (int kc = 0; kc < 4; ++kc) {
        #pragma unroll
        for (int i = 0; i < 16; ++i) {
            int idx = t + i * 256;
            int kk = idx >> 7, cc = idx & 127;
            lw[kk][cc] = W[(size_t)(kc * 32 + kk) * HID + cc];
        }
        int gr = base + sr;
        #pragma unroll
        for (int i = 0; i < 4; ++i) {
            int k0 = (sg * 4 + i) * 4;
            float4 vy = make_float4(0.f, 0.f, 0.f, 0.f);
            if (gr < n) vy = *(const float4*)(y + (size_t)gr * HID + kc * 32 + k0);
            int gk = kc * 32 + k0;
            ly[k0 + 0][sr] = fmaf(vy.x, scale[gk + 0], shift[gk + 0]);
            ly[k0 + 1][sr] = fmaf(vy.y, scale[gk + 1], shift[gk + 1]);
            ly[k0 + 2][sr] = fmaf(vy.z, scale[gk + 2], shift[gk + 2]);
            ly[k0 + 3][sr] = fmaf(vy.w, scale[gk + 3], shift[gk + 3]);
        }
        __syncthreads();
        #pragma unroll
        for (int k = 0; k < 32; ++k) {
            float4 w0 = *(const float4*)&lw[k][c8];
            float4 w1 = *(const float4*)&lw[k][c8 + 4];
            float4 ya = *(const float4*)&ly[k][rg * 8];
            float4 yb = *(const float4*)&ly[k][rg * 8 + 4];
            float yv[8] = {ya.x, ya.y, ya.z, ya.w, yb.x, yb.y, yb.z, yb.w};
            float wv[8] = {w0.x, w0.y, w0.z, w0.w, w1.x, w1.y, w1.z, w1.w};
            #pragma unroll
            for (int r = 0; r < 8; ++r)
                #pragma unroll
                for (int c = 0; c < 8; ++c)
                    acc[r][c] = fmaf(yv[r], wv[c], acc[r][c]);
        }
        __syncthreads();
    }
    #pragma unroll
    for (int r = 0; r < 8; ++r) {
        int gr = base + rg * 8 + r;
        if (gr < n) {
            uint4 p;
            p.x = pack2bf(acc[r][0], acc[r][1]);
            p.y = pack2bf(acc[r][2], acc[r][3]);
            p.z = pack2bf(acc[r][4], acc[r][5]);
            p.w = pack2bf(acc[r][6], acc[r][7]);
            *(uint4*)&out[(size_t)gr * HID + c8] = p;
        }
    }
}

extern "C" void kernel_launch(void* const* d_in, const int* in_sizes, int n_in,
                              void* d_out, int out_size, void* d_ws, size_t ws_size,
                              hipStream_t stream) {
    const float* x     = (const float*)d_in[0];
    const void*  ei    = d_in[1];
    const float* W1    = (const float*)d_in[2];
    const float* b1    = (const float*)d_in[3];
    const float* gamma = (const float*)d_in[4];
    const float* beta  = (const float*)d_in[5];
    const float* W2    = (const float*)d_in[6];
    const float* b2    = (const float*)d_in[7];
    float* out = (float*)d_out;

    const int f_in = 25;
    int n = in_sizes[0] / f_in;
    int E = in_sizes[1] / 2;
    int nb = (n + 255) >> 8;    // 256-node scan chunks

    char* ws = (char*)d_ws;
    size_t off = 0;
    auto alloc = [&](size_t bytes) -> void* {
        void* p = ws + off;
        off += (bytes + 511) & ~(size_t)511;
        return p;
    };
    int*   cnt        = (int*)alloc((size_t)n * 4);
    int*   rowptr     = (int*)alloc(((size_t)n + 1) * 4);
    int*   cursor     = (int*)alloc((size_t)n * 4);
    float* dinv       = (float*)alloc((size_t)n * 4);
    int*   edge_src   = (int*)alloc((size_t)E * 4);
    float* bnacc      = (float*)alloc(256 * 4);   // sum[128] ++ sumsq[128]
    float* sclshift   = (float*)alloc(256 * 4);   // scale[128] ++ shift[128]
    int*   mode       = (int*)alloc(4);
    int*   blocksum   = (int*)alloc((size_t)nb * 4);
    int*   blockoff   = (int*)alloc((size_t)nb * 4);
    unsigned short* h = (unsigned short*)alloc((size_t)n * HID * 2);  // bf16 h1, then h2

    hipMemsetAsync(cnt, 0, (size_t)n * 4, stream);
    hipMemsetAsync(bnacc, 0, 256 * 4, stream);

    detect_kernel<<<1, 256, 0, stream>>>((const unsigned int*)ei, mode, 2 * E);
    count_kernel<<<(E + 255) / 256, 256, 0, stream>>>(ei, mode, cnt, E);
    scan_partial_kernel<<<nb, 256, 0, stream>>>(cnt, blocksum, n);
    scan_blocksums_kernel<<<1, 1024, 0, stream>>>(blocksum, blockoff, rowptr, nb, n);
    scan_finalize_kernel<<<nb, 256, 0, stream>>>(cnt, blockoff, rowptr, cursor, dinv, n);
    // 8 groups x 784 blocks; consecutive blockIdx -> groups 0..7 (XCD round-robin)
    scatter_part_kernel<<<8 * 784, 256, 0, stream>>>(ei, mode, cursor, edge_src, E);

    // layer 1: h1 = bf16(x@W1) ; y1 = relu(prop(h1) + b1) -> stored in d_out (fp32)
    gemm1_kernel<<<4096, 256, 0, stream>>>(x, W1, h, n);
    propagate_kernel<<<(n + 3) / 4, 256, 0, stream>>>(h, rowptr, edge_src, dinv, b1, out, n);

    // batchnorm stats on y1
    bn_stats_kernel<<<512, 256, 0, stream>>>(out, bnacc, bnacc + 128, n);
    bn_finalize_kernel<<<1, 128, 0, stream>>>(bnacc, bnacc + 128, gamma, beta,
                                              sclshift, sclshift + 128, 1.0f / (float)n);

    // layer 2: h2 = bf16(bn(y1)@W2) ; out = relu(prop(h2) + b2)
    gemm2_kernel<<<(n + 127) / 128, 256, 0, stream>>>(out, W2, sclshift, sclshift + 128, h, n);
    propagate_kernel<<<(n + 3) / 4, 256, 0, stream>>>(h, rowptr, edge_src, dinv, b2, out, n);
}